// Round 6
// baseline (1359.111 us; speedup 1.0000x reference)
//
#include <hip/hip_runtime.h>

#define NN 100000
#define CC 128
#define EE 200000
#define TT 3
#define NCHUNK 98   // ceil(NN/1024)

typedef __attribute__((ext_vector_type(8))) __bf16 bf16x8;
typedef __attribute__((ext_vector_type(8))) unsigned short ushort8;
typedef __attribute__((ext_vector_type(4))) float f32x4;

union U8 { ushort8 u; bf16x8 b; };

__device__ __forceinline__ unsigned short f2bf(float v) {
    unsigned u = __float_as_uint(v);
    u += 0x7fffu + ((u >> 16) & 1u);          // RNE
    return (unsigned short)(u >> 16);
}
__device__ __forceinline__ float bf2f(unsigned short h) {
    return __uint_as_float(((unsigned)h) << 16);
}
// split 8 fp32 into hi/lo bf16 fragments (a ~= hi + lo, |err| ~ 2^-17 |a|)
__device__ __forceinline__ void split8(const float* f, bf16x8& hi, bf16x8& lo) {
    U8 h, l;
    #pragma unroll
    for (int j = 0; j < 8; ++j) {
        float v = f[j];
        unsigned short hs = f2bf(v);
        h.u[j] = hs;
        l.u[j] = f2bf(v - bf2f(hs));
    }
    hi = h.b; lo = l.b;
}

// ---------------- pack: split Wq/Wk/Wv and Wf into bf16 hi/lo (ORIGINAL [c][k] layout = B^T frag layout) ----------------
__global__ __launch_bounds__(256) void k_pack(
    const float* __restrict__ Wq, const float* __restrict__ bq,
    const float* __restrict__ Wk, const float* __restrict__ bk,
    const float* __restrict__ Wv, const float* __restrict__ bv,
    const float* __restrict__ Wf,
    unsigned short* __restrict__ Whi3, unsigned short* __restrict__ Wlo3,
    unsigned short* __restrict__ Wfhi, unsigned short* __restrict__ Wflo,
    float* __restrict__ Bpack)
{
    int idx = blockIdx.x * 256 + threadIdx.x;   // 0..16383
    int y = blockIdx.y;                          // 0..12
    if (y < 9) {
        int t = y / 3, m = y % 3;
        const float* W = (m == 0 ? Wq : m == 1 ? Wk : Wv) + t * CC * CC;
        float v = W[idx];
        unsigned short hs = f2bf(v);
        Whi3[y * CC * CC + idx] = hs;
        Wlo3[y * CC * CC + idx] = f2bf(v - bf2f(hs));
    } else if (y < 12) {
        int lin = (y - 9) * 16384 + idx;         // 0..49151 over Wf [128][384]
        float v = Wf[lin];
        unsigned short hs = f2bf(v);
        Wfhi[lin] = hs;
        Wflo[lin] = f2bf(v - bf2f(hs));
    } else {
        if (idx < 9 * CC) {
            int mm = idx >> 7, c = idx & 127;
            int t = mm / 3, m = mm % 3;
            const float* b = (m == 0 ? bq : m == 1 ? bk : bv);
            Bpack[idx] = b[t * CC + c];
        }
    }
}

// ---------------- WcombT[c][k] = sum_t sum_j Ws[t][j][k]*Wf[c][t*128+j] (skip path folded), split hi/lo; bconst fp32 ----------------
__global__ __launch_bounds__(256) void k_wcomb(
    const float* __restrict__ Ws, const float* __restrict__ bs,
    const float* __restrict__ Wf, const float* __restrict__ bf,
    unsigned short* __restrict__ Wch, unsigned short* __restrict__ Wcl,
    float* __restrict__ bconst)
{
    int b = blockIdx.x;
    if (b < 64) {
        int idx = b * 256 + threadIdx.x;
        int k = idx >> 7, c = idx & 127;
        float s = 0.f;
        for (int t = 0; t < TT; ++t) {
            const float* wsp = Ws + t * CC * CC;
            const float* wfp = Wf + (size_t)c * (TT * CC) + t * CC;
            for (int j = 0; j < CC; ++j)
                s += wsp[j * CC + k] * wfp[j];
        }
        unsigned short hs = f2bf(s);
        Wch[c * CC + k] = hs;
        Wcl[c * CC + k] = f2bf(s - bf2f(hs));
    } else {
        int c = threadIdx.x;
        if (c < CC) {
            float s = bf[c];
            for (int t = 0; t < TT; ++t) {
                const float* wfp = Wf + (size_t)c * (TT * CC) + t * CC;
                for (int j = 0; j < CC; ++j)
                    s += bs[t * CC + j] * wfp[j];
            }
            bconst[c] = s;
        }
    }
}

// ---------------- CSR build (unchanged, measured working) ----------------
__global__ __launch_bounds__(256) void k_count(const int* __restrict__ dst, int* __restrict__ deg) {
    int idx = blockIdx.x * 256 + threadIdx.x;
    if (idx >= TT * EE) return;
    int t = idx / EE;
    atomicAdd(&deg[t * NN + dst[idx]], 1);
}

__global__ __launch_bounds__(256) void k_scan1(const int* __restrict__ deg,
                                               int* __restrict__ incl, int* __restrict__ bsums) {
    int t = blockIdx.y, b = blockIdx.x, tid = threadIdx.x;
    const int* d = deg + t * NN;
    int base = b * 1024 + tid * 4;
    int v0 = (base + 0 < NN) ? d[base + 0] : 0;
    int v1 = (base + 1 < NN) ? d[base + 1] : 0;
    int v2 = (base + 2 < NN) ? d[base + 2] : 0;
    int v3 = (base + 3 < NN) ? d[base + 3] : 0;
    v1 += v0; v2 += v1; v3 += v2;
    __shared__ int lds[256];
    lds[tid] = v3;
    for (int off = 1; off < 256; off <<= 1) {
        __syncthreads();
        int x = (tid >= off) ? lds[tid - off] : 0;
        __syncthreads();
        lds[tid] += x;
    }
    __syncthreads();
    int excl = lds[tid] - v3;
    if (base + 0 < NN) incl[t * NN + base + 0] = excl + v0;
    if (base + 1 < NN) incl[t * NN + base + 1] = excl + v1;
    if (base + 2 < NN) incl[t * NN + base + 2] = excl + v2;
    if (base + 3 < NN) incl[t * NN + base + 3] = excl + v3;
    if (tid == 255) bsums[t * NCHUNK + b] = lds[255];
}

__global__ __launch_bounds__(128) void k_scan2(const int* __restrict__ bsums, int* __restrict__ bexcl) {
    int t = blockIdx.y, tid = threadIdx.x;
    __shared__ int lds[128];
    int v = (tid < NCHUNK) ? bsums[t * NCHUNK + tid] : 0;
    lds[tid] = v;
    for (int off = 1; off < 128; off <<= 1) {
        __syncthreads();
        int x = (tid >= off) ? lds[tid - off] : 0;
        __syncthreads();
        lds[tid] += x;
    }
    if (tid < NCHUNK) bexcl[t * NCHUNK + tid] = lds[tid] - v;
}

__global__ __launch_bounds__(256) void k_scan3(const int* __restrict__ deg, const int* __restrict__ incl,
                                               const int* __restrict__ bexcl,
                                               int* __restrict__ offs, int* __restrict__ cursor) {
    int t = blockIdx.y, b = blockIdx.x, tid = threadIdx.x;
    int add = bexcl[t * NCHUNK + b];
    int base = b * 1024 + tid * 4;
    #pragma unroll
    for (int j = 0; j < 4; j++) {
        int i = base + j;
        if (i < NN) {
            int e = incl[t * NN + i] - deg[t * NN + i] + add;
            offs[t * NN + i] = e;
            cursor[t * NN + i] = e;
        }
    }
}

__global__ __launch_bounds__(256) void k_scatter(const int* __restrict__ src, const int* __restrict__ dst,
                                                 int* __restrict__ cursor, int* __restrict__ csr_src) {
    int idx = blockIdx.x * 256 + threadIdx.x;
    if (idx >= TT * EE) return;
    int t = idx / EE;
    int d = dst[idx];
    int pos = atomicAdd(&cursor[t * NN + d], 1);
    csr_src[t * EE + pos] = src[idx];
}

// ---------------- split-bf16 MFMA: Q,K,V for one type. 64 rows/block, 4 waves x 16 rows, no LDS ----------------
__global__ __launch_bounds__(256) void k_mg3(
    const float* __restrict__ x,
    const unsigned short* __restrict__ Whi, const unsigned short* __restrict__ Wlo,
    const float* __restrict__ B3,
    float* __restrict__ Q, float* __restrict__ K, float* __restrict__ V)
{
    int wid = threadIdx.x >> 6, l = threadIdx.x & 63;
    int lan = l & 15, kb = l >> 4;
    int rb = blockIdx.x * 64 + wid * 16;

    // A fragments for this wave's 16 rows: lane l holds row rb+lan, k = kt*32 + kb*8 .. +8
    bf16x8 ah[4], al[4];
    {
        int arow = rb + lan;
        const float* xp = x + (size_t)arow * CC + kb * 8;
        #pragma unroll
        for (int kt = 0; kt < 4; ++kt) {
            float tmp[8];
            if (arow < NN) {
                float4 p0 = *(const float4*)(xp + kt * 32);
                float4 p1 = *(const float4*)(xp + kt * 32 + 4);
                tmp[0] = p0.x; tmp[1] = p0.y; tmp[2] = p0.z; tmp[3] = p0.w;
                tmp[4] = p1.x; tmp[5] = p1.y; tmp[6] = p1.z; tmp[7] = p1.w;
            } else {
                #pragma unroll
                for (int j = 0; j < 8; ++j) tmp[j] = 0.f;
            }
            split8(tmp, ah[kt], al[kt]);
        }
    }

    #pragma unroll 1
    for (int m = 0; m < 3; ++m) {
        const unsigned short* wh = Whi + m * CC * CC;
        const unsigned short* wl = Wlo + m * CC * CC;
        f32x4 acc[8];
        #pragma unroll
        for (int nt = 0; nt < 8; ++nt)
            #pragma unroll
            for (int i = 0; i < 4; ++i) acc[nt][i] = 0.f;

        #pragma unroll
        for (int kt = 0; kt < 4; ++kt) {
            U8 bh[8], bl[8];
            #pragma unroll
            for (int nt = 0; nt < 8; ++nt) {
                size_t wo = (size_t)(nt * 16 + lan) * CC + kt * 32 + kb * 8;
                bh[nt].u = *(const ushort8*)(wh + wo);
                bl[nt].u = *(const ushort8*)(wl + wo);
            }
            #pragma unroll
            for (int nt = 0; nt < 8; ++nt) {
                acc[nt] = __builtin_amdgcn_mfma_f32_16x16x32_bf16(ah[kt], bl[nt].b, acc[nt], 0, 0, 0);
                acc[nt] = __builtin_amdgcn_mfma_f32_16x16x32_bf16(al[kt], bh[nt].b, acc[nt], 0, 0, 0);
                acc[nt] = __builtin_amdgcn_mfma_f32_16x16x32_bf16(ah[kt], bh[nt].b, acc[nt], 0, 0, 0);
            }
        }

        float* dst = (m == 0 ? Q : m == 1 ? K : V);
        #pragma unroll
        for (int nt = 0; nt < 8; ++nt) {
            int col = nt * 16 + lan;
            float bias = B3[m * CC + col];
            #pragma unroll
            for (int i = 0; i < 4; ++i) {
                int grow = rb + kb * 4 + i;       // D layout: row=(l>>4)*4+reg, col=l&15 [m89]
                if (grow < NN)
                    dst[(size_t)grow * CC + col] = acc[nt][i] + bias;
            }
        }
    }
}

// ---------------- split-bf16 MFMA fusion: out (+)= X0@W0 [+ X1@W1] (+ bconst) ----------------
__global__ __launch_bounds__(256) void k_mfuse(
    const float* __restrict__ X0,
    const unsigned short* __restrict__ W0h, const unsigned short* __restrict__ W0l,
    int ldb0, int koff0,
    const float* __restrict__ X1,
    const unsigned short* __restrict__ W1h, const unsigned short* __restrict__ W1l,
    int ldb1, int koff1,
    const float* __restrict__ bias, float* __restrict__ out, int accum)
{
    int wid = threadIdx.x >> 6, l = threadIdx.x & 63;
    int lan = l & 15, kb = l >> 4;
    int rb = blockIdx.x * 64 + wid * 16;

    f32x4 acc[8];
    #pragma unroll
    for (int nt = 0; nt < 8; ++nt)
        #pragma unroll
        for (int i = 0; i < 4; ++i) acc[nt][i] = 0.f;

    #pragma unroll 1
    for (int s = 0; s < 2; ++s) {
        const float* X = s ? X1 : X0;
        if (!X) break;
        const unsigned short* wh = s ? W1h : W0h;
        const unsigned short* wl = s ? W1l : W0l;
        int ldb  = s ? ldb1 : ldb0;
        int koff = s ? koff1 : koff0;

        bf16x8 ah[4], al[4];
        {
            int arow = rb + lan;
            const float* xp = X + (size_t)arow * CC + kb * 8;
            #pragma unroll
            for (int kt = 0; kt < 4; ++kt) {
                float tmp[8];
                if (arow < NN) {
                    float4 p0 = *(const float4*)(xp + kt * 32);
                    float4 p1 = *(const float4*)(xp + kt * 32 + 4);
                    tmp[0] = p0.x; tmp[1] = p0.y; tmp[2] = p0.z; tmp[3] = p0.w;
                    tmp[4] = p1.x; tmp[5] = p1.y; tmp[6] = p1.z; tmp[7] = p1.w;
                } else {
                    #pragma unroll
                    for (int j = 0; j < 8; ++j) tmp[j] = 0.f;
                }
                split8(tmp, ah[kt], al[kt]);
            }
        }

        #pragma unroll
        for (int kt = 0; kt < 4; ++kt) {
            U8 bh[8], bl[8];
            #pragma unroll
            for (int nt = 0; nt < 8; ++nt) {
                size_t wo = (size_t)(nt * 16 + lan) * ldb + koff + kt * 32 + kb * 8;
                bh[nt].u = *(const ushort8*)(wh + wo);
                bl[nt].u = *(const ushort8*)(wl + wo);
            }
            #pragma unroll
            for (int nt = 0; nt < 8; ++nt) {
                acc[nt] = __builtin_amdgcn_mfma_f32_16x16x32_bf16(ah[kt], bl[nt].b, acc[nt], 0, 0, 0);
                acc[nt] = __builtin_amdgcn_mfma_f32_16x16x32_bf16(al[kt], bh[nt].b, acc[nt], 0, 0, 0);
                acc[nt] = __builtin_amdgcn_mfma_f32_16x16x32_bf16(ah[kt], bh[nt].b, acc[nt], 0, 0, 0);
            }
        }
    }

    #pragma unroll
    for (int nt = 0; nt < 8; ++nt) {
        int col = nt * 16 + lan;
        #pragma unroll
        for (int i = 0; i < 4; ++i) {
            int grow = rb + kb * 4 + i;
            if (grow < NN) {
                float* op = out + (size_t)grow * CC + col;
                float v = acc[nt][i];
                v += accum ? *op : bias[col];
                *op = v;
            }
        }
    }
}

// ---------------- per-node attention aggregation -> A fp32 (unchanged) ----------------
__global__ __launch_bounds__(256) void k_agg(
    const float* __restrict__ Q, const float* __restrict__ Kx,
    const float* __restrict__ V, float* __restrict__ A,
    const int* __restrict__ offs, const int* __restrict__ deg, const int* __restrict__ csr)
{
    int wid = threadIdx.x >> 6;
    int lane = threadIdx.x & 63;
    int n = blockIdx.x * 4 + wid;
    if (n >= NN) return;
    int dg = deg[n];
    if (dg == 0) {
        A[(size_t)n * CC + lane] = 0.f;
        A[(size_t)n * CC + 64 + lane] = 0.f;
        return;
    }
    const float scale = 0.17677669529663687f;  // 1/sqrt(32)
    float q0 = Q[(size_t)n * CC + lane];
    float q1 = Q[(size_t)n * CC + 64 + lane];
    float acc0 = 0.f, acc1 = 0.f, den0 = 0.f, den1 = 0.f;
    int off = offs[n];
    for (int i = 0; i < dg; i++) {
        int s = csr[off + i];
        const float* kb = Kx + (size_t)s * CC;
        const float* vb = V + (size_t)s * CC;
        float k0 = kb[lane], k1 = kb[64 + lane];
        float v0 = vb[lane], v1 = vb[64 + lane];
        float d0 = q0 * k0, d1 = q1 * k1;
        #pragma unroll
        for (int m = 16; m >= 1; m >>= 1) {
            d0 += __shfl_xor(d0, m);
            d1 += __shfl_xor(d1, m);
        }
        float e0 = expf(d0 * scale), e1 = expf(d1 * scale);
        acc0 += e0 * v0; den0 += e0;
        acc1 += e1 * v1; den1 += e1;
    }
    A[(size_t)n * CC + lane]      = acc0 / (den0 + 1e-16f);
    A[(size_t)n * CC + 64 + lane] = acc1 / (den1 + 1e-16f);
}

extern "C" void kernel_launch(void* const* d_in, const int* in_sizes, int n_in,
                              void* d_out, int out_size, void* d_ws, size_t ws_size,
                              hipStream_t stream)
{
    const float* x   = (const float*)d_in[0];
    const int*   src = (const int*)d_in[1];
    const int*   dst = (const int*)d_in[2];
    const float* Wq  = (const float*)d_in[3];
    const float* bq  = (const float*)d_in[4];
    const float* Wk  = (const float*)d_in[5];
    const float* bk  = (const float*)d_in[6];
    const float* Wv  = (const float*)d_in[7];
    const float* bv  = (const float*)d_in[8];
    const float* Ws  = (const float*)d_in[9];
    const float* bs  = (const float*)d_in[10];
    const float* Wf  = (const float*)d_in[11];
    const float* bf  = (const float*)d_in[12];
    float* out = (float*)d_out;

    char* ws = (char*)d_ws;
    size_t o = 0;
    auto alloc = [&](size_t bytes) -> char* {
        char* p = ws + o;
        o = (o + bytes + 255) & ~(size_t)255;
        return p;
    };
    unsigned short* Whi3 = (unsigned short*)alloc((size_t)9 * CC * CC * 2);
    unsigned short* Wlo3 = (unsigned short*)alloc((size_t)9 * CC * CC * 2);
    unsigned short* Wfhi = (unsigned short*)alloc((size_t)CC * TT * CC * 2);
    unsigned short* Wflo = (unsigned short*)alloc((size_t)CC * TT * CC * 2);
    unsigned short* Wch  = (unsigned short*)alloc((size_t)CC * CC * 2);
    unsigned short* Wcl  = (unsigned short*)alloc((size_t)CC * CC * 2);
    float* Bpack  = (float*)alloc((size_t)9 * CC * 4);
    float* bconst = (float*)alloc((size_t)CC * 4);
    int* deg      = (int*)alloc((size_t)TT * NN * 4);
    int* incl     = (int*)alloc((size_t)TT * NN * 4);
    int* bsums    = (int*)alloc((size_t)TT * NCHUNK * 4);
    int* bexcl    = (int*)alloc((size_t)TT * NCHUNK * 4);
    int* offs     = (int*)alloc((size_t)TT * NN * 4);
    int* cursor   = (int*)alloc((size_t)TT * NN * 4);
    int* csr_src  = (int*)alloc((size_t)TT * EE * 4);
    float* Qb = (float*)alloc((size_t)NN * CC * 4);
    float* Kb = (float*)alloc((size_t)NN * CC * 4);
    float* Vb = (float*)alloc((size_t)NN * CC * 4);
    float* Ab = (float*)alloc((size_t)NN * CC * 4);

    hipMemsetAsync(deg, 0, (size_t)TT * NN * 4, stream);
    k_pack<<<dim3(64, 13), 256, 0, stream>>>(Wq, bq, Wk, bk, Wv, bv, Wf,
                                             Whi3, Wlo3, Wfhi, Wflo, Bpack);
    k_wcomb<<<65, 256, 0, stream>>>(Ws, bs, Wf, bf, Wch, Wcl, bconst);
    k_count<<<(TT * EE + 255) / 256, 256, 0, stream>>>(dst, deg);
    k_scan1<<<dim3(NCHUNK, TT), 256, 0, stream>>>(deg, incl, bsums);
    k_scan2<<<dim3(1, TT), 128, 0, stream>>>(bsums, bexcl);
    k_scan3<<<dim3(NCHUNK, TT), 256, 0, stream>>>(deg, incl, bexcl, offs, cursor);
    k_scatter<<<(TT * EE + 255) / 256, 256, 0, stream>>>(src, dst, cursor, csr_src);

    int gblocks = (NN + 63) / 64;   // 1563
    for (int t = 0; t < TT; t++) {
        k_mg3<<<gblocks, 256, 0, stream>>>(x, Whi3 + (size_t)t * 3 * CC * CC,
                                           Wlo3 + (size_t)t * 3 * CC * CC,
                                           Bpack + t * 3 * CC, Qb, Kb, Vb);
        k_agg<<<(NN + 3) / 4, 256, 0, stream>>>(Qb, Kb, Vb, Ab,
                                                offs + t * NN, deg + t * NN, csr_src + (size_t)t * EE);
        if (t == 0)
            k_mfuse<<<gblocks, 256, 0, stream>>>(x, Wch, Wcl, CC, 0,
                                                 Ab, Wfhi, Wflo, TT * CC, 0,
                                                 bconst, out, 0);
        else
            k_mfuse<<<gblocks, 256, 0, stream>>>(Ab, Wfhi, Wflo, TT * CC, t * CC,
                                                 nullptr, nullptr, nullptr, 0, 0,
                                                 bconst, out, 1);
    }
}

// Round 7
// 1178.534 us; speedup vs baseline: 1.1532x; 1.1532x over previous
//
#include <hip/hip_runtime.h>

#define NN 100000
#define CC 128
#define EE 200000
#define TT 3
#define NCHUNK 98   // ceil(NN/1024)

typedef __attribute__((ext_vector_type(8))) __bf16 bf16x8;
typedef __attribute__((ext_vector_type(8))) unsigned short ushort8;
typedef __attribute__((ext_vector_type(4))) float f32x4;

union U8 { ushort8 u; bf16x8 b; };

__device__ __forceinline__ unsigned short f2bf(float v) {
    unsigned u = __float_as_uint(v);
    u += 0x7fffu + ((u >> 16) & 1u);          // RNE
    return (unsigned short)(u >> 16);
}
__device__ __forceinline__ float bf2f(unsigned short h) {
    return __uint_as_float(((unsigned)h) << 16);
}
// split 8 fp32 into hi/lo bf16 fragments (a ~= hi + lo, |err| ~ 2^-17 |a|)
__device__ __forceinline__ void split8(const float* f, bf16x8& hi, bf16x8& lo) {
    U8 h, l;
    #pragma unroll
    for (int j = 0; j < 8; ++j) {
        float v = f[j];
        unsigned short hs = f2bf(v);
        h.u[j] = hs;
        l.u[j] = f2bf(v - bf2f(hs));
    }
    hi = h.b; lo = l.b;
}

// load one A row-tile k-slice (8 fp32) and split
__device__ __forceinline__ void loadA(const float* __restrict__ X, int arow, int kt, int kb,
                                      bf16x8& hi, bf16x8& lo) {
    float tmp[8];
    if (arow < NN) {
        const float* xp = X + (size_t)arow * CC + kt * 32 + kb * 8;
        float4 p0 = *(const float4*)xp;
        float4 p1 = *(const float4*)(xp + 4);
        tmp[0] = p0.x; tmp[1] = p0.y; tmp[2] = p0.z; tmp[3] = p0.w;
        tmp[4] = p1.x; tmp[5] = p1.y; tmp[6] = p1.z; tmp[7] = p1.w;
    } else {
        #pragma unroll
        for (int j = 0; j < 8; ++j) tmp[j] = 0.f;
    }
    split8(tmp, hi, lo);
}

// ---------------- pack: split Wq/Wk/Wv and Wf into bf16 hi/lo (ORIGINAL [c][k] layout = B^T frag layout) ----------------
__global__ __launch_bounds__(256) void k_pack(
    const float* __restrict__ Wq, const float* __restrict__ bq,
    const float* __restrict__ Wk, const float* __restrict__ bk,
    const float* __restrict__ Wv, const float* __restrict__ bv,
    const float* __restrict__ Wf,
    unsigned short* __restrict__ Whi3, unsigned short* __restrict__ Wlo3,
    unsigned short* __restrict__ Wfhi, unsigned short* __restrict__ Wflo,
    float* __restrict__ Bpack)
{
    int idx = blockIdx.x * 256 + threadIdx.x;   // 0..16383
    int y = blockIdx.y;                          // 0..12
    if (y < 9) {
        int t = y / 3, m = y % 3;
        const float* W = (m == 0 ? Wq : m == 1 ? Wk : Wv) + t * CC * CC;
        float v = W[idx];
        unsigned short hs = f2bf(v);
        Whi3[y * CC * CC + idx] = hs;
        Wlo3[y * CC * CC + idx] = f2bf(v - bf2f(hs));
    } else if (y < 12) {
        int lin = (y - 9) * 16384 + idx;         // 0..49151 over Wf [128][384]
        float v = Wf[lin];
        unsigned short hs = f2bf(v);
        Wfhi[lin] = hs;
        Wflo[lin] = f2bf(v - bf2f(hs));
    } else {
        if (idx < 9 * CC) {
            int mm = idx >> 7, c = idx & 127;
            int t = mm / 3, m = mm % 3;
            const float* b = (m == 0 ? bq : m == 1 ? bk : bv);
            Bpack[idx] = b[t * CC + c];
        }
    }
}

// ---------------- WcombT[c][k] = sum_t sum_j Ws[t][j][k]*Wf[c][t*128+j] (skip path folded), split hi/lo; bconst fp32 ----------------
__global__ __launch_bounds__(256) void k_wcomb(
    const float* __restrict__ Ws, const float* __restrict__ bs,
    const float* __restrict__ Wf, const float* __restrict__ bf,
    unsigned short* __restrict__ Wch, unsigned short* __restrict__ Wcl,
    float* __restrict__ bconst)
{
    int b = blockIdx.x;
    if (b < 64) {
        int idx = b * 256 + threadIdx.x;
        int k = idx >> 7, c = idx & 127;
        float s = 0.f;
        for (int t = 0; t < TT; ++t) {
            const float* wsp = Ws + t * CC * CC;
            const float* wfp = Wf + (size_t)c * (TT * CC) + t * CC;
            for (int j = 0; j < CC; ++j)
                s += wsp[j * CC + k] * wfp[j];
        }
        unsigned short hs = f2bf(s);
        Wch[c * CC + k] = hs;
        Wcl[c * CC + k] = f2bf(s - bf2f(hs));
    } else {
        int c = threadIdx.x;
        if (c < CC) {
            float s = bf[c];
            for (int t = 0; t < TT; ++t) {
                const float* wfp = Wf + (size_t)c * (TT * CC) + t * CC;
                for (int j = 0; j < CC; ++j)
                    s += bs[t * CC + j] * wfp[j];
            }
            bconst[c] = s;
        }
    }
}

// ---------------- CSR build (unchanged, measured working) ----------------
__global__ __launch_bounds__(256) void k_count(const int* __restrict__ dst, int* __restrict__ deg) {
    int idx = blockIdx.x * 256 + threadIdx.x;
    if (idx >= TT * EE) return;
    int t = idx / EE;
    atomicAdd(&deg[t * NN + dst[idx]], 1);
}

__global__ __launch_bounds__(256) void k_scan1(const int* __restrict__ deg,
                                               int* __restrict__ incl, int* __restrict__ bsums) {
    int t = blockIdx.y, b = blockIdx.x, tid = threadIdx.x;
    const int* d = deg + t * NN;
    int base = b * 1024 + tid * 4;
    int v0 = (base + 0 < NN) ? d[base + 0] : 0;
    int v1 = (base + 1 < NN) ? d[base + 1] : 0;
    int v2 = (base + 2 < NN) ? d[base + 2] : 0;
    int v3 = (base + 3 < NN) ? d[base + 3] : 0;
    v1 += v0; v2 += v1; v3 += v2;
    __shared__ int lds[256];
    lds[tid] = v3;
    for (int off = 1; off < 256; off <<= 1) {
        __syncthreads();
        int x = (tid >= off) ? lds[tid - off] : 0;
        __syncthreads();
        lds[tid] += x;
    }
    __syncthreads();
    int excl = lds[tid] - v3;
    if (base + 0 < NN) incl[t * NN + base + 0] = excl + v0;
    if (base + 1 < NN) incl[t * NN + base + 1] = excl + v1;
    if (base + 2 < NN) incl[t * NN + base + 2] = excl + v2;
    if (base + 3 < NN) incl[t * NN + base + 3] = excl + v3;
    if (tid == 255) bsums[t * NCHUNK + b] = lds[255];
}

__global__ __launch_bounds__(128) void k_scan2(const int* __restrict__ bsums, int* __restrict__ bexcl) {
    int t = blockIdx.y, tid = threadIdx.x;
    __shared__ int lds[128];
    int v = (tid < NCHUNK) ? bsums[t * NCHUNK + tid] : 0;
    lds[tid] = v;
    for (int off = 1; off < 128; off <<= 1) {
        __syncthreads();
        int x = (tid >= off) ? lds[tid - off] : 0;
        __syncthreads();
        lds[tid] += x;
    }
    if (tid < NCHUNK) bexcl[t * NCHUNK + tid] = lds[tid] - v;
}

__global__ __launch_bounds__(256) void k_scan3(const int* __restrict__ deg, const int* __restrict__ incl,
                                               const int* __restrict__ bexcl,
                                               int* __restrict__ offs, int* __restrict__ cursor) {
    int t = blockIdx.y, b = blockIdx.x, tid = threadIdx.x;
    int add = bexcl[t * NCHUNK + b];
    int base = b * 1024 + tid * 4;
    #pragma unroll
    for (int j = 0; j < 4; j++) {
        int i = base + j;
        if (i < NN) {
            int e = incl[t * NN + i] - deg[t * NN + i] + add;
            offs[t * NN + i] = e;
            cursor[t * NN + i] = e;
        }
    }
}

__global__ __launch_bounds__(256) void k_scatter(const int* __restrict__ src, const int* __restrict__ dst,
                                                 int* __restrict__ cursor, int* __restrict__ csr_src) {
    int idx = blockIdx.x * 256 + threadIdx.x;
    if (idx >= TT * EE) return;
    int t = idx / EE;
    int d = dst[idx];
    int pos = atomicAdd(&cursor[t * NN + d], 1);
    csr_src[t * EE + pos] = src[idx];
}

// ---------------- split-bf16 MFMA: Q,K,V for one type. 128 rows/block, 4 waves x 32 rows ----------------
__global__ __launch_bounds__(256, 2) void k_mg3(
    const float* __restrict__ x,
    const unsigned short* __restrict__ Whi, const unsigned short* __restrict__ Wlo,
    const float* __restrict__ B3,
    float* __restrict__ Q, float* __restrict__ K, float* __restrict__ V)
{
    int wid = threadIdx.x >> 6, l = threadIdx.x & 63;
    int lan = l & 15, kb = l >> 4;
    int rb = blockIdx.x * 128 + wid * 32;

    // A fragments: 2 row-tiles x 4 k-tiles
    bf16x8 ah[2][4], al[2][4];
    #pragma unroll
    for (int rt = 0; rt < 2; ++rt)
        #pragma unroll
        for (int kt = 0; kt < 4; ++kt)
            loadA(x, rb + rt * 16 + lan, kt, kb, ah[rt][kt], al[rt][kt]);

    #pragma unroll 1
    for (int m = 0; m < 3; ++m) {
        const unsigned short* wh = Whi + m * CC * CC;
        const unsigned short* wl = Wlo + m * CC * CC;
        f32x4 acc[2][8];
        #pragma unroll
        for (int rt = 0; rt < 2; ++rt)
            #pragma unroll
            for (int nt = 0; nt < 8; ++nt)
                #pragma unroll
                for (int i = 0; i < 4; ++i) acc[rt][nt][i] = 0.f;

        #pragma unroll
        for (int kt = 0; kt < 4; ++kt) {
            #pragma unroll
            for (int nc = 0; nc < 2; ++nc) {           // 4-col-tile chunks
                U8 bh[4], bl[4];
                #pragma unroll
                for (int j = 0; j < 4; ++j) {
                    size_t wo = (size_t)((nc * 4 + j) * 16 + lan) * CC + kt * 32 + kb * 8;
                    bh[j].u = *(const ushort8*)(wh + wo);
                    bl[j].u = *(const ushort8*)(wl + wo);
                }
                #pragma unroll
                for (int j = 0; j < 4; ++j) {
                    int nt = nc * 4 + j;
                    #pragma unroll
                    for (int rt = 0; rt < 2; ++rt) {
                        acc[rt][nt] = __builtin_amdgcn_mfma_f32_16x16x32_bf16(ah[rt][kt], bl[j].b, acc[rt][nt], 0, 0, 0);
                        acc[rt][nt] = __builtin_amdgcn_mfma_f32_16x16x32_bf16(al[rt][kt], bh[j].b, acc[rt][nt], 0, 0, 0);
                        acc[rt][nt] = __builtin_amdgcn_mfma_f32_16x16x32_bf16(ah[rt][kt], bh[j].b, acc[rt][nt], 0, 0, 0);
                    }
                }
            }
        }

        float* dst = (m == 0 ? Q : m == 1 ? K : V);
        #pragma unroll
        for (int nt = 0; nt < 8; ++nt) {
            int col = nt * 16 + lan;
            float bias = B3[m * CC + col];
            #pragma unroll
            for (int rt = 0; rt < 2; ++rt)
                #pragma unroll
                for (int i = 0; i < 4; ++i) {
                    int grow = rb + rt * 16 + kb * 4 + i;   // D: row=(l>>4)*4+reg, col=l&15 [m89]
                    if (grow < NN)
                        dst[(size_t)grow * CC + col] = acc[rt][nt][i] + bias;
                }
        }
    }
}

// ---------------- split-bf16 MFMA fusion: out (+)= X0@W0 [+ X1@W1] (+ bconst), 128 rows/block ----------------
__global__ __launch_bounds__(256, 2) void k_mfuse(
    const float* __restrict__ X0,
    const unsigned short* __restrict__ W0h, const unsigned short* __restrict__ W0l,
    int ldb0, int koff0,
    const float* __restrict__ X1,
    const unsigned short* __restrict__ W1h, const unsigned short* __restrict__ W1l,
    int ldb1, int koff1,
    const float* __restrict__ bias, float* __restrict__ out, int accum)
{
    int wid = threadIdx.x >> 6, l = threadIdx.x & 63;
    int lan = l & 15, kb = l >> 4;
    int rb = blockIdx.x * 128 + wid * 32;

    f32x4 acc[2][8];
    #pragma unroll
    for (int rt = 0; rt < 2; ++rt)
        #pragma unroll
        for (int nt = 0; nt < 8; ++nt)
            #pragma unroll
            for (int i = 0; i < 4; ++i) acc[rt][nt][i] = 0.f;

    #pragma unroll 1
    for (int s = 0; s < 2; ++s) {
        const float* X = s ? X1 : X0;
        if (!X) break;
        const unsigned short* wh = s ? W1h : W0h;
        const unsigned short* wl = s ? W1l : W0l;
        int ldb  = s ? ldb1 : ldb0;
        int koff = s ? koff1 : koff0;

        bf16x8 ah[2][4], al[2][4];
        #pragma unroll
        for (int rt = 0; rt < 2; ++rt)
            #pragma unroll
            for (int kt = 0; kt < 4; ++kt)
                loadA(X, rb + rt * 16 + lan, kt, kb, ah[rt][kt], al[rt][kt]);

        #pragma unroll
        for (int kt = 0; kt < 4; ++kt) {
            #pragma unroll
            for (int nc = 0; nc < 2; ++nc) {
                U8 bh[4], bl[4];
                #pragma unroll
                for (int j = 0; j < 4; ++j) {
                    size_t wo = (size_t)((nc * 4 + j) * 16 + lan) * ldb + koff + kt * 32 + kb * 8;
                    bh[j].u = *(const ushort8*)(wh + wo);
                    bl[j].u = *(const ushort8*)(wl + wo);
                }
                #pragma unroll
                for (int j = 0; j < 4; ++j) {
                    int nt = nc * 4 + j;
                    #pragma unroll
                    for (int rt = 0; rt < 2; ++rt) {
                        acc[rt][nt] = __builtin_amdgcn_mfma_f32_16x16x32_bf16(ah[rt][kt], bl[j].b, acc[rt][nt], 0, 0, 0);
                        acc[rt][nt] = __builtin_amdgcn_mfma_f32_16x16x32_bf16(al[rt][kt], bh[j].b, acc[rt][nt], 0, 0, 0);
                        acc[rt][nt] = __builtin_amdgcn_mfma_f32_16x16x32_bf16(ah[rt][kt], bh[j].b, acc[rt][nt], 0, 0, 0);
                    }
                }
            }
        }
    }

    #pragma unroll
    for (int nt = 0; nt < 8; ++nt) {
        int col = nt * 16 + lan;
        #pragma unroll
        for (int rt = 0; rt < 2; ++rt)
            #pragma unroll
            for (int i = 0; i < 4; ++i) {
                int grow = rb + rt * 16 + kb * 4 + i;
                if (grow < NN) {
                    float* op = out + (size_t)grow * CC + col;
                    float v = acc[rt][nt][i];
                    v += accum ? *op : bias[col];
                    *op = v;
                }
            }
    }
}

// ---------------- per-node attention aggregation -> A fp32 (unchanged) ----------------
__global__ __launch_bounds__(256) void k_agg(
    const float* __restrict__ Q, const float* __restrict__ Kx,
    const float* __restrict__ V, float* __restrict__ A,
    const int* __restrict__ offs, const int* __restrict__ deg, const int* __restrict__ csr)
{
    int wid = threadIdx.x >> 6;
    int lane = threadIdx.x & 63;
    int n = blockIdx.x * 4 + wid;
    if (n >= NN) return;
    int dg = deg[n];
    if (dg == 0) {
        A[(size_t)n * CC + lane] = 0.f;
        A[(size_t)n * CC + 64 + lane] = 0.f;
        return;
    }
    const float scale = 0.17677669529663687f;  // 1/sqrt(32)
    float q0 = Q[(size_t)n * CC + lane];
    float q1 = Q[(size_t)n * CC + 64 + lane];
    float acc0 = 0.f, acc1 = 0.f, den0 = 0.f, den1 = 0.f;
    int off = offs[n];
    for (int i = 0; i < dg; i++) {
        int s = csr[off + i];
        const float* kb = Kx + (size_t)s * CC;
        const float* vb = V + (size_t)s * CC;
        float k0 = kb[lane], k1 = kb[64 + lane];
        float v0 = vb[lane], v1 = vb[64 + lane];
        float d0 = q0 * k0, d1 = q1 * k1;
        #pragma unroll
        for (int m = 16; m >= 1; m >>= 1) {
            d0 += __shfl_xor(d0, m);
            d1 += __shfl_xor(d1, m);
        }
        float e0 = expf(d0 * scale), e1 = expf(d1 * scale);
        acc0 += e0 * v0; den0 += e0;
        acc1 += e1 * v1; den1 += e1;
    }
    A[(size_t)n * CC + lane]      = acc0 / (den0 + 1e-16f);
    A[(size_t)n * CC + 64 + lane] = acc1 / (den1 + 1e-16f);
}

extern "C" void kernel_launch(void* const* d_in, const int* in_sizes, int n_in,
                              void* d_out, int out_size, void* d_ws, size_t ws_size,
                              hipStream_t stream)
{
    const float* x   = (const float*)d_in[0];
    const int*   src = (const int*)d_in[1];
    const int*   dst = (const int*)d_in[2];
    const float* Wq  = (const float*)d_in[3];
    const float* bq  = (const float*)d_in[4];
    const float* Wk  = (const float*)d_in[5];
    const float* bk  = (const float*)d_in[6];
    const float* Wv  = (const float*)d_in[7];
    const float* bv  = (const float*)d_in[8];
    const float* Ws  = (const float*)d_in[9];
    const float* bs  = (const float*)d_in[10];
    const float* Wf  = (const float*)d_in[11];
    const float* bf  = (const float*)d_in[12];
    float* out = (float*)d_out;

    char* ws = (char*)d_ws;
    size_t o = 0;
    auto alloc = [&](size_t bytes) -> char* {
        char* p = ws + o;
        o = (o + bytes + 255) & ~(size_t)255;
        return p;
    };
    unsigned short* Whi3 = (unsigned short*)alloc((size_t)9 * CC * CC * 2);
    unsigned short* Wlo3 = (unsigned short*)alloc((size_t)9 * CC * CC * 2);
    unsigned short* Wfhi = (unsigned short*)alloc((size_t)CC * TT * CC * 2);
    unsigned short* Wflo = (unsigned short*)alloc((size_t)CC * TT * CC * 2);
    unsigned short* Wch  = (unsigned short*)alloc((size_t)CC * CC * 2);
    unsigned short* Wcl  = (unsigned short*)alloc((size_t)CC * CC * 2);
    float* Bpack  = (float*)alloc((size_t)9 * CC * 4);
    float* bconst = (float*)alloc((size_t)CC * 4);
    int* deg      = (int*)alloc((size_t)TT * NN * 4);
    int* incl     = (int*)alloc((size_t)TT * NN * 4);
    int* bsums    = (int*)alloc((size_t)TT * NCHUNK * 4);
    int* bexcl    = (int*)alloc((size_t)TT * NCHUNK * 4);
    int* offs     = (int*)alloc((size_t)TT * NN * 4);
    int* cursor   = (int*)alloc((size_t)TT * NN * 4);
    int* csr_src  = (int*)alloc((size_t)TT * EE * 4);
    float* Qb = (float*)alloc((size_t)NN * CC * 4);
    float* Kb = (float*)alloc((size_t)NN * CC * 4);
    float* Vb = (float*)alloc((size_t)NN * CC * 4);
    float* Ab = (float*)alloc((size_t)NN * CC * 4);

    hipMemsetAsync(deg, 0, (size_t)TT * NN * 4, stream);
    k_pack<<<dim3(64, 13), 256, 0, stream>>>(Wq, bq, Wk, bk, Wv, bv, Wf,
                                             Whi3, Wlo3, Wfhi, Wflo, Bpack);
    k_wcomb<<<65, 256, 0, stream>>>(Ws, bs, Wf, bf, Wch, Wcl, bconst);
    k_count<<<(TT * EE + 255) / 256, 256, 0, stream>>>(dst, deg);
    k_scan1<<<dim3(NCHUNK, TT), 256, 0, stream>>>(deg, incl, bsums);
    k_scan2<<<dim3(1, TT), 128, 0, stream>>>(bsums, bexcl);
    k_scan3<<<dim3(NCHUNK, TT), 256, 0, stream>>>(deg, incl, bexcl, offs, cursor);
    k_scatter<<<(TT * EE + 255) / 256, 256, 0, stream>>>(src, dst, cursor, csr_src);

    int gblocks = (NN + 127) / 128;   // 782
    for (int t = 0; t < TT; t++) {
        k_mg3<<<gblocks, 256, 0, stream>>>(x, Whi3 + (size_t)t * 3 * CC * CC,
                                           Wlo3 + (size_t)t * 3 * CC * CC,
                                           Bpack + t * 3 * CC, Qb, Kb, Vb);
        k_agg<<<(NN + 3) / 4, 256, 0, stream>>>(Qb, Kb, Vb, Ab,
                                                offs + t * NN, deg + t * NN, csr_src + (size_t)t * EE);
        if (t == 0)
            k_mfuse<<<gblocks, 256, 0, stream>>>(x, Wch, Wcl, CC, 0,
                                                 Ab, Wfhi, Wflo, TT * CC, 0,
                                                 bconst, out, 0);
        else
            k_mfuse<<<gblocks, 256, 0, stream>>>(Ab, Wfhi, Wflo, TT * CC, t * CC,
                                                 nullptr, nullptr, nullptr, 0, 0,
                                                 bconst, out, 1);
    }
}

// Round 8
// 916.702 us; speedup vs baseline: 1.4826x; 1.2856x over previous
//
#include <hip/hip_runtime.h>

#define NN 100000
#define CC 128
#define EE 200000
#define TT 3
#define NCHUNK 98   // ceil(NN/1024)

typedef __attribute__((ext_vector_type(8))) __bf16 bf16x8;
typedef __attribute__((ext_vector_type(8))) unsigned short ushort8;
typedef __attribute__((ext_vector_type(4))) float f32x4;

union U8 { ushort8 u; bf16x8 b; };

__device__ __forceinline__ unsigned short f2bf(float v) {
    unsigned u = __float_as_uint(v);
    u += 0x7fffu + ((u >> 16) & 1u);          // RNE
    return (unsigned short)(u >> 16);
}
__device__ __forceinline__ float bf2f(unsigned short h) {
    return __uint_as_float(((unsigned)h) << 16);
}
// split 8 fp32 into hi/lo bf16 fragments (a ~= hi + lo, |err| ~ 2^-17 |a|)
__device__ __forceinline__ void split8(const float* f, bf16x8& hi, bf16x8& lo) {
    U8 h, l;
    #pragma unroll
    for (int j = 0; j < 8; ++j) {
        float v = f[j];
        unsigned short hs = f2bf(v);
        h.u[j] = hs;
        l.u[j] = f2bf(v - bf2f(hs));
    }
    hi = h.b; lo = l.b;
}

// load one A row-tile k-slice (8 fp32) and split
__device__ __forceinline__ void loadA(const float* __restrict__ X, int arow, int kt, int kb,
                                      bf16x8& hi, bf16x8& lo) {
    float tmp[8];
    if (arow < NN) {
        const float* xp = X + (size_t)arow * CC + kt * 32 + kb * 8;
        float4 p0 = *(const float4*)xp;
        float4 p1 = *(const float4*)(xp + 4);
        tmp[0] = p0.x; tmp[1] = p0.y; tmp[2] = p0.z; tmp[3] = p0.w;
        tmp[4] = p1.x; tmp[5] = p1.y; tmp[6] = p1.z; tmp[7] = p1.w;
    } else {
        #pragma unroll
        for (int j = 0; j < 8; ++j) tmp[j] = 0.f;
    }
    split8(tmp, hi, lo);
}

// fragment-major offset: frag (kt,nt), lane l, elem j  ->  ((kt*8+nt)*64+l)*8+j
// holds W[c][k] with c = nt*16+(l&15), k = kt*32+(l>>4)*8+j

// ---------------- pack: split W into bf16 hi/lo FRAGMENT-MAJOR (coalesced wave loads) ----------------
__global__ __launch_bounds__(256) void k_pack(
    const float* __restrict__ Wq, const float* __restrict__ bq,
    const float* __restrict__ Wk, const float* __restrict__ bk,
    const float* __restrict__ Wv, const float* __restrict__ bv,
    const float* __restrict__ Wf,
    unsigned short* __restrict__ Whi3, unsigned short* __restrict__ Wlo3,
    unsigned short* __restrict__ Wfhi, unsigned short* __restrict__ Wflo,
    float* __restrict__ Bpack)
{
    int idx = blockIdx.x * 256 + threadIdx.x;   // 0..16383
    int y = blockIdx.y;                          // 0..12
    // decompose output fragment index
    int j  = idx & 7;
    int l  = (idx >> 3) & 63;
    int nt = (idx >> 9) & 7;
    int kt = idx >> 12;
    int c = nt * 16 + (l & 15);
    int k = kt * 32 + ((l >> 4) << 3) + j;
    if (y < 9) {
        int t = y / 3, m = y % 3;
        const float* W = (m == 0 ? Wq : m == 1 ? Wk : Wv) + t * CC * CC;
        float v = W[c * CC + k];
        unsigned short hs = f2bf(v);
        Whi3[y * CC * CC + idx] = hs;
        Wlo3[y * CC * CC + idx] = f2bf(v - bf2f(hs));
    } else if (y < 12) {
        int t = y - 9;
        float v = Wf[(size_t)c * (TT * CC) + t * CC + k];
        unsigned short hs = f2bf(v);
        Wfhi[t * CC * CC + idx] = hs;
        Wflo[t * CC * CC + idx] = f2bf(v - bf2f(hs));
    } else {
        if (idx < 9 * CC) {
            int mm = idx >> 7, cc2 = idx & 127;
            int t = mm / 3, m = mm % 3;
            const float* b = (m == 0 ? bq : m == 1 ? bk : bv);
            Bpack[idx] = b[t * CC + cc2];
        }
    }
}

// ---------------- Wcomb (skip path folded through fusion), written FRAGMENT-MAJOR; bconst fp32 ----------------
__global__ __launch_bounds__(256) void k_wcomb(
    const float* __restrict__ Ws, const float* __restrict__ bs,
    const float* __restrict__ Wf, const float* __restrict__ bf,
    unsigned short* __restrict__ Wch, unsigned short* __restrict__ Wcl,
    float* __restrict__ bconst)
{
    int b = blockIdx.x;
    if (b < 64) {
        int idx = b * 256 + threadIdx.x;
        int k = idx >> 7, c = idx & 127;
        float s = 0.f;
        for (int t = 0; t < TT; ++t) {
            const float* wsp = Ws + t * CC * CC;
            const float* wfp = Wf + (size_t)c * (TT * CC) + t * CC;
            for (int j = 0; j < CC; ++j)
                s += wsp[j * CC + k] * wfp[j];
        }
        // fragment-major position of (c,k)
        int kt = k >> 5, kb = (k >> 3) & 3, j = k & 7;
        int l = (c & 15) + (kb << 4);
        int nt = c >> 4;
        int o = (((kt * 8 + nt) * 64) + l) * 8 + j;
        unsigned short hs = f2bf(s);
        Wch[o] = hs;
        Wcl[o] = f2bf(s - bf2f(hs));
    } else {
        int c = threadIdx.x;
        if (c < CC) {
            float s = bf[c];
            for (int t = 0; t < TT; ++t) {
                const float* wfp = Wf + (size_t)c * (TT * CC) + t * CC;
                for (int j = 0; j < CC; ++j)
                    s += bs[t * CC + j] * wfp[j];
            }
            bconst[c] = s;
        }
    }
}

// ---------------- CSR build (unchanged, measured working) ----------------
__global__ __launch_bounds__(256) void k_count(const int* __restrict__ dst, int* __restrict__ deg) {
    int idx = blockIdx.x * 256 + threadIdx.x;
    if (idx >= TT * EE) return;
    int t = idx / EE;
    atomicAdd(&deg[t * NN + dst[idx]], 1);
}

__global__ __launch_bounds__(256) void k_scan1(const int* __restrict__ deg,
                                               int* __restrict__ incl, int* __restrict__ bsums) {
    int t = blockIdx.y, b = blockIdx.x, tid = threadIdx.x;
    const int* d = deg + t * NN;
    int base = b * 1024 + tid * 4;
    int v0 = (base + 0 < NN) ? d[base + 0] : 0;
    int v1 = (base + 1 < NN) ? d[base + 1] : 0;
    int v2 = (base + 2 < NN) ? d[base + 2] : 0;
    int v3 = (base + 3 < NN) ? d[base + 3] : 0;
    v1 += v0; v2 += v1; v3 += v2;
    __shared__ int lds[256];
    lds[tid] = v3;
    for (int off = 1; off < 256; off <<= 1) {
        __syncthreads();
        int x = (tid >= off) ? lds[tid - off] : 0;
        __syncthreads();
        lds[tid] += x;
    }
    __syncthreads();
    int excl = lds[tid] - v3;
    if (base + 0 < NN) incl[t * NN + base + 0] = excl + v0;
    if (base + 1 < NN) incl[t * NN + base + 1] = excl + v1;
    if (base + 2 < NN) incl[t * NN + base + 2] = excl + v2;
    if (base + 3 < NN) incl[t * NN + base + 3] = excl + v3;
    if (tid == 255) bsums[t * NCHUNK + b] = lds[255];
}

__global__ __launch_bounds__(128) void k_scan2(const int* __restrict__ bsums, int* __restrict__ bexcl) {
    int t = blockIdx.y, tid = threadIdx.x;
    __shared__ int lds[128];
    int v = (tid < NCHUNK) ? bsums[t * NCHUNK + tid] : 0;
    lds[tid] = v;
    for (int off = 1; off < 128; off <<= 1) {
        __syncthreads();
        int x = (tid >= off) ? lds[tid - off] : 0;
        __syncthreads();
        lds[tid] += x;
    }
    if (tid < NCHUNK) bexcl[t * NCHUNK + tid] = lds[tid] - v;
}

__global__ __launch_bounds__(256) void k_scan3(const int* __restrict__ deg, const int* __restrict__ incl,
                                               const int* __restrict__ bexcl,
                                               int* __restrict__ offs, int* __restrict__ cursor) {
    int t = blockIdx.y, b = blockIdx.x, tid = threadIdx.x;
    int add = bexcl[t * NCHUNK + b];
    int base = b * 1024 + tid * 4;
    #pragma unroll
    for (int j = 0; j < 4; j++) {
        int i = base + j;
        if (i < NN) {
            int e = incl[t * NN + i] - deg[t * NN + i] + add;
            offs[t * NN + i] = e;
            cursor[t * NN + i] = e;
        }
    }
}

__global__ __launch_bounds__(256) void k_scatter(const int* __restrict__ src, const int* __restrict__ dst,
                                                 int* __restrict__ cursor, int* __restrict__ csr_src) {
    int idx = blockIdx.x * 256 + threadIdx.x;
    if (idx >= TT * EE) return;
    int t = idx / EE;
    int d = dst[idx];
    int pos = atomicAdd(&cursor[t * NN + d], 1);
    csr_src[t * EE + pos] = src[idx];
}

// ---------------- split-bf16 MFMA: Q,K,V for one type. 128 rows/block, 4 waves x 32 rows ----------------
__global__ __launch_bounds__(256, 2) void k_mg3(
    const float* __restrict__ x,
    const unsigned short* __restrict__ Whi, const unsigned short* __restrict__ Wlo,
    const float* __restrict__ B3,
    float* __restrict__ Q, float* __restrict__ K, float* __restrict__ V)
{
    int wid = threadIdx.x >> 6, l = threadIdx.x & 63;
    int lan = l & 15, kb = l >> 4;
    int rb = blockIdx.x * 128 + wid * 32;

    // A fragments: 2 row-tiles x 4 k-tiles
    bf16x8 ah[2][4], al[2][4];
    #pragma unroll
    for (int rt = 0; rt < 2; ++rt)
        #pragma unroll
        for (int kt = 0; kt < 4; ++kt)
            loadA(x, rb + rt * 16 + lan, kt, kb, ah[rt][kt], al[rt][kt]);

    #pragma unroll 1
    for (int m = 0; m < 3; ++m) {
        const unsigned short* wh = Whi + m * CC * CC;
        const unsigned short* wl = Wlo + m * CC * CC;
        f32x4 acc[2][8];
        #pragma unroll
        for (int rt = 0; rt < 2; ++rt)
            #pragma unroll
            for (int nt = 0; nt < 8; ++nt)
                #pragma unroll
                for (int i = 0; i < 4; ++i) acc[rt][nt][i] = 0.f;

        #pragma unroll
        for (int kt = 0; kt < 4; ++kt) {
            #pragma unroll
            for (int nc = 0; nc < 2; ++nc) {           // 4-col-tile chunks
                U8 bh[4], bl[4];
                #pragma unroll
                for (int j = 0; j < 4; ++j) {
                    // fragment-major: contiguous 1KB per wave load
                    size_t wo = ((size_t)(kt * 8 + nc * 4 + j) * 64 + l) * 8;
                    bh[j].u = *(const ushort8*)(wh + wo);
                    bl[j].u = *(const ushort8*)(wl + wo);
                }
                #pragma unroll
                for (int j = 0; j < 4; ++j) {
                    int nt = nc * 4 + j;
                    #pragma unroll
                    for (int rt = 0; rt < 2; ++rt) {
                        acc[rt][nt] = __builtin_amdgcn_mfma_f32_16x16x32_bf16(ah[rt][kt], bl[j].b, acc[rt][nt], 0, 0, 0);
                        acc[rt][nt] = __builtin_amdgcn_mfma_f32_16x16x32_bf16(al[rt][kt], bh[j].b, acc[rt][nt], 0, 0, 0);
                        acc[rt][nt] = __builtin_amdgcn_mfma_f32_16x16x32_bf16(ah[rt][kt], bh[j].b, acc[rt][nt], 0, 0, 0);
                    }
                }
            }
        }

        float* dst = (m == 0 ? Q : m == 1 ? K : V);
        #pragma unroll
        for (int nt = 0; nt < 8; ++nt) {
            int col = nt * 16 + lan;
            float bias = B3[m * CC + col];
            #pragma unroll
            for (int rt = 0; rt < 2; ++rt)
                #pragma unroll
                for (int i = 0; i < 4; ++i) {
                    int grow = rb + rt * 16 + kb * 4 + i;   // D: row=(l>>4)*4+reg, col=l&15 [m89]
                    if (grow < NN)
                        dst[(size_t)grow * CC + col] = acc[rt][nt][i] + bias;
                }
        }
    }
}

// ---------------- split-bf16 MFMA fusion: out (+)= X0@W0 [+ X1@W1] (+ bconst), 128 rows/block ----------------
__global__ __launch_bounds__(256, 2) void k_mfuse(
    const float* __restrict__ X0,
    const unsigned short* __restrict__ W0h, const unsigned short* __restrict__ W0l,
    const float* __restrict__ X1,
    const unsigned short* __restrict__ W1h, const unsigned short* __restrict__ W1l,
    const float* __restrict__ bias, float* __restrict__ out, int accum)
{
    int wid = threadIdx.x >> 6, l = threadIdx.x & 63;
    int lan = l & 15, kb = l >> 4;
    int rb = blockIdx.x * 128 + wid * 32;

    f32x4 acc[2][8];
    #pragma unroll
    for (int rt = 0; rt < 2; ++rt)
        #pragma unroll
        for (int nt = 0; nt < 8; ++nt)
            #pragma unroll
            for (int i = 0; i < 4; ++i) acc[rt][nt][i] = 0.f;

    #pragma unroll 1
    for (int s = 0; s < 2; ++s) {
        const float* X = s ? X1 : X0;
        if (!X) break;
        const unsigned short* wh = s ? W1h : W0h;
        const unsigned short* wl = s ? W1l : W0l;

        bf16x8 ah[2][4], al[2][4];
        #pragma unroll
        for (int rt = 0; rt < 2; ++rt)
            #pragma unroll
            for (int kt = 0; kt < 4; ++kt)
                loadA(X, rb + rt * 16 + lan, kt, kb, ah[rt][kt], al[rt][kt]);

        #pragma unroll
        for (int kt = 0; kt < 4; ++kt) {
            #pragma unroll
            for (int nc = 0; nc < 2; ++nc) {
                U8 bh[4], bl[4];
                #pragma unroll
                for (int j = 0; j < 4; ++j) {
                    size_t wo = ((size_t)(kt * 8 + nc * 4 + j) * 64 + l) * 8;
                    bh[j].u = *(const ushort8*)(wh + wo);
                    bl[j].u = *(const ushort8*)(wl + wo);
                }
                #pragma unroll
                for (int j = 0; j < 4; ++j) {
                    int nt = nc * 4 + j;
                    #pragma unroll
                    for (int rt = 0; rt < 2; ++rt) {
                        acc[rt][nt] = __builtin_amdgcn_mfma_f32_16x16x32_bf16(ah[rt][kt], bl[j].b, acc[rt][nt], 0, 0, 0);
                        acc[rt][nt] = __builtin_amdgcn_mfma_f32_16x16x32_bf16(al[rt][kt], bh[j].b, acc[rt][nt], 0, 0, 0);
                        acc[rt][nt] = __builtin_amdgcn_mfma_f32_16x16x32_bf16(ah[rt][kt], bh[j].b, acc[rt][nt], 0, 0, 0);
                    }
                }
            }
        }
    }

    #pragma unroll
    for (int nt = 0; nt < 8; ++nt) {
        int col = nt * 16 + lan;
        #pragma unroll
        for (int rt = 0; rt < 2; ++rt)
            #pragma unroll
            for (int i = 0; i < 4; ++i) {
                int grow = rb + rt * 16 + kb * 4 + i;
                if (grow < NN) {
                    float* op = out + (size_t)grow * CC + col;
                    float v = acc[rt][nt][i];
                    v += accum ? *op : bias[col];
                    *op = v;
                }
            }
    }
}

// ---------------- per-node attention aggregation -> A fp32 (unchanged) ----------------
__global__ __launch_bounds__(256) void k_agg(
    const float* __restrict__ Q, const float* __restrict__ Kx,
    const float* __restrict__ V, float* __restrict__ A,
    const int* __restrict__ offs, const int* __restrict__ deg, const int* __restrict__ csr)
{
    int wid = threadIdx.x >> 6;
    int lane = threadIdx.x & 63;
    int n = blockIdx.x * 4 + wid;
    if (n >= NN) return;
    int dg = deg[n];
    if (dg == 0) {
        A[(size_t)n * CC + lane] = 0.f;
        A[(size_t)n * CC + 64 + lane] = 0.f;
        return;
    }
    const float scale = 0.17677669529663687f;  // 1/sqrt(32)
    float q0 = Q[(size_t)n * CC + lane];
    float q1 = Q[(size_t)n * CC + 64 + lane];
    float acc0 = 0.f, acc1 = 0.f, den0 = 0.f, den1 = 0.f;
    int off = offs[n];
    for (int i = 0; i < dg; i++) {
        int s = csr[off + i];
        const float* kb = Kx + (size_t)s * CC;
        const float* vb = V + (size_t)s * CC;
        float k0 = kb[lane], k1 = kb[64 + lane];
        float v0 = vb[lane], v1 = vb[64 + lane];
        float d0 = q0 * k0, d1 = q1 * k1;
        #pragma unroll
        for (int m = 16; m >= 1; m >>= 1) {
            d0 += __shfl_xor(d0, m);
            d1 += __shfl_xor(d1, m);
        }
        float e0 = expf(d0 * scale), e1 = expf(d1 * scale);
        acc0 += e0 * v0; den0 += e0;
        acc1 += e1 * v1; den1 += e1;
    }
    A[(size_t)n * CC + lane]      = acc0 / (den0 + 1e-16f);
    A[(size_t)n * CC + 64 + lane] = acc1 / (den1 + 1e-16f);
}

extern "C" void kernel_launch(void* const* d_in, const int* in_sizes, int n_in,
                              void* d_out, int out_size, void* d_ws, size_t ws_size,
                              hipStream_t stream)
{
    const float* x   = (const float*)d_in[0];
    const int*   src = (const int*)d_in[1];
    const int*   dst = (const int*)d_in[2];
    const float* Wq  = (const float*)d_in[3];
    const float* bq  = (const float*)d_in[4];
    const float* Wk  = (const float*)d_in[5];
    const float* bk  = (const float*)d_in[6];
    const float* Wv  = (const float*)d_in[7];
    const float* bv  = (const float*)d_in[8];
    const float* Ws  = (const float*)d_in[9];
    const float* bs  = (const float*)d_in[10];
    const float* Wf  = (const float*)d_in[11];
    const float* bf  = (const float*)d_in[12];
    float* out = (float*)d_out;

    char* ws = (char*)d_ws;
    size_t o = 0;
    auto alloc = [&](size_t bytes) -> char* {
        char* p = ws + o;
        o = (o + bytes + 255) & ~(size_t)255;
        return p;
    };
    unsigned short* Whi3 = (unsigned short*)alloc((size_t)9 * CC * CC * 2);
    unsigned short* Wlo3 = (unsigned short*)alloc((size_t)9 * CC * CC * 2);
    unsigned short* Wfhi = (unsigned short*)alloc((size_t)TT * CC * CC * 2);
    unsigned short* Wflo = (unsigned short*)alloc((size_t)TT * CC * CC * 2);
    unsigned short* Wch  = (unsigned short*)alloc((size_t)CC * CC * 2);
    unsigned short* Wcl  = (unsigned short*)alloc((size_t)CC * CC * 2);
    float* Bpack  = (float*)alloc((size_t)9 * CC * 4);
    float* bconst = (float*)alloc((size_t)CC * 4);
    int* deg      = (int*)alloc((size_t)TT * NN * 4);
    int* incl     = (int*)alloc((size_t)TT * NN * 4);
    int* bsums    = (int*)alloc((size_t)TT * NCHUNK * 4);
    int* bexcl    = (int*)alloc((size_t)TT * NCHUNK * 4);
    int* offs     = (int*)alloc((size_t)TT * NN * 4);
    int* cursor   = (int*)alloc((size_t)TT * NN * 4);
    int* csr_src  = (int*)alloc((size_t)TT * EE * 4);
    float* Qb = (float*)alloc((size_t)NN * CC * 4);
    float* Kb = (float*)alloc((size_t)NN * CC * 4);
    float* Vb = (float*)alloc((size_t)NN * CC * 4);
    float* Ab = (float*)alloc((size_t)NN * CC * 4);

    hipMemsetAsync(deg, 0, (size_t)TT * NN * 4, stream);
    k_pack<<<dim3(64, 13), 256, 0, stream>>>(Wq, bq, Wk, bk, Wv, bv, Wf,
                                             Whi3, Wlo3, Wfhi, Wflo, Bpack);
    k_wcomb<<<65, 256, 0, stream>>>(Ws, bs, Wf, bf, Wch, Wcl, bconst);
    k_count<<<(TT * EE + 255) / 256, 256, 0, stream>>>(dst, deg);
    k_scan1<<<dim3(NCHUNK, TT), 256, 0, stream>>>(deg, incl, bsums);
    k_scan2<<<dim3(1, TT), 128, 0, stream>>>(bsums, bexcl);
    k_scan3<<<dim3(NCHUNK, TT), 256, 0, stream>>>(deg, incl, bexcl, offs, cursor);
    k_scatter<<<(TT * EE + 255) / 256, 256, 0, stream>>>(src, dst, cursor, csr_src);

    int gblocks = (NN + 127) / 128;   // 782
    for (int t = 0; t < TT; t++) {
        k_mg3<<<gblocks, 256, 0, stream>>>(x, Whi3 + (size_t)t * 3 * CC * CC,
                                           Wlo3 + (size_t)t * 3 * CC * CC,
                                           Bpack + t * 3 * CC, Qb, Kb, Vb);
        k_agg<<<(NN + 3) / 4, 256, 0, stream>>>(Qb, Kb, Vb, Ab,
                                                offs + t * NN, deg + t * NN, csr_src + (size_t)t * EE);
        if (t == 0)
            k_mfuse<<<gblocks, 256, 0, stream>>>(x, Wch, Wcl,
                                                 Ab, Wfhi, Wflo,
                                                 bconst, out, 0);
        else
            k_mfuse<<<gblocks, 256, 0, stream>>>(Ab, Wfhi + (size_t)t * CC * CC, Wflo + (size_t)t * CC * CC,
                                                 nullptr, nullptr, nullptr,
                                                 bconst, out, 1);
    }
}